// Round 4
// baseline (382.497 us; speedup 1.0000x reference)
//
#include <hip/hip_runtime.h>
#include <math.h>

typedef short short8 __attribute__((ext_vector_type(8)));
typedef float f32x4 __attribute__((ext_vector_type(4)));
typedef unsigned short u16;
typedef unsigned int u32;

#define S_TOK 4096
#define DM 768
#define DF 3072
#define NE 8
#define NSLOT (S_TOK*2)      // 8192 real slots
#define PSLOT 9216           // padded capacity (8192 + 8*127 rounded up)
#define MBMAX 72             // PSLOT/128
#define MB64  144            // PSLOT/64 (gemm2 M-tiles)

// ---- control block ----
// counts/cursor are cacheline-padded: expert e lives at [e*16] (64 B stride)
#define WS_COUNTS   0        // 128 ints (8 x 16-int stride)
#define WS_CURSOR   512      // 128 ints
#define WS_OFFS     1024     // 9 ints (padded expert starts)
#define WS_MBE      1088     // MBMAX ints (mb -> expert, -1 = dead)
#define WS_EID      2048     // NSLOT ints
#define WS_GW       (WS_EID + NSLOT*4)
#define WS_POS      (WS_GW  + NSLOT*4)      // NSLOT ints: slot position of (token,k)
#define WS_TOK      (WS_POS + NSLOT*4)      // PSLOT ints
#define CTRL_BYTES  262144

#define AS1 __attribute__((address_space(1)))
#define AS3 __attribute__((address_space(3)))
#define GLDS16(g, s) __builtin_amdgcn_global_load_lds((const AS1 u32*)(g), (AS3 u32*)(s), 16, 0, 0)

__device__ inline u16 f2b(float f){
    u32 u = __builtin_bit_cast(u32, f);
    u32 r = (u + 0x7fffu + ((u >> 16) & 1u)) >> 16;   // RNE
    return (u16)r;
}
__device__ inline short8 ldcvt8f(const float* p){
    float4 a = *(const float4*)p;
    float4 b = *(const float4*)(p + 4);
    short8 v;
    v[0]=(short)f2b(a.x); v[1]=(short)f2b(a.y); v[2]=(short)f2b(a.z); v[3]=(short)f2b(a.w);
    v[4]=(short)f2b(b.x); v[5]=(short)f2b(b.y); v[6]=(short)f2b(b.z); v[7]=(short)f2b(b.w);
    return v;
}

// ---------------- gate: grid-stride waves + LDS histogram + padded atomics ----------------
#define GATE_BLOCKS 128
__global__ __launch_bounds__(256) void gate_kernel(const float* __restrict__ x, const float* __restrict__ Wg,
                                                   int* __restrict__ eid, float* __restrict__ gw,
                                                   int* __restrict__ counts){
    __shared__ int lh[NE];
    int t = threadIdx.x;
    if (t < NE) lh[t] = 0;
    __syncthreads();
    int wv = t >> 6, l = t & 63;
    int wgid = blockIdx.x*4 + wv;            // 0 .. GATE_BLOCKS*4-1
    const int NW = GATE_BLOCKS*4;

    for (int s = wgid; s < S_TOK; s += NW){
        float acc[NE];
#pragma unroll
        for (int e = 0; e < NE; e++) acc[e] = 0.f;
        const float* xr = x + (size_t)s * DM;
#pragma unroll
        for (int i = 0; i < DM/64; i++){
            int d = l + 64*i;
            float xv = xr[d];
            float4 w0 = *(const float4*)(Wg + d*NE);
            float4 w1 = *(const float4*)(Wg + d*NE + 4);
            acc[0] += xv*w0.x; acc[1] += xv*w0.y; acc[2] += xv*w0.z; acc[3] += xv*w0.w;
            acc[4] += xv*w1.x; acc[5] += xv*w1.y; acc[6] += xv*w1.z; acc[7] += xv*w1.w;
        }
#pragma unroll
        for (int e = 0; e < NE; e++){
#pragma unroll
            for (int off = 32; off; off >>= 1) acc[e] += __shfl_down(acc[e], off);
        }
        if (l == 0){
            int i1 = 0; float v1 = acc[0];
            for (int e = 1; e < NE; e++) if (acc[e] > v1){ v1 = acc[e]; i1 = e; }
            int i2 = -1; float v2 = -1e30f;
            for (int e = 0; e < NE; e++) if (e != i1 && acc[e] > v2){ v2 = acc[e]; i2 = e; }
            float w0, w1;
            if (i2 < 0){ i2 = (i1 + 1) & 7; w0 = 1.f; w1 = 0.f; }
            else {
                float e2 = expf(v2 - v1);
                w0 = 1.f / (1.f + e2);
                w1 = e2 / (1.f + e2);
            }
            eid[2*s]   = i1; gw[2*s]   = w0;
            eid[2*s+1] = i2; gw[2*s+1] = w1;
            atomicAdd(&lh[i1], 1);
            atomicAdd(&lh[i2], 1);
        }
    }
    __syncthreads();
    if (t < NE && lh[t] > 0) atomicAdd(&counts[t*16], lh[t]);
}

// ---------------- offsets with capacity padding + mb->expert map ----------------
__global__ void offsets_kernel(const int* __restrict__ counts, int* __restrict__ offs,
                               int* __restrict__ cursor, int* __restrict__ mbe){
    if (threadIdx.x == 0 && blockIdx.x == 0){
        int P = 0;
        for (int e = 0; e < NE; e++){
            offs[e] = P; cursor[e*16] = P;
            int padded = ((counts[e*16] + 127) >> 7) << 7;
            for (int mb = P >> 7; mb < (P + padded) >> 7; mb++) mbe[mb] = e;
            P += padded;
        }
        offs[NE] = P;
        for (int mb = P >> 7; mb < MBMAX; mb++) mbe[mb] = -1;
    }
}

// ---------------- scatter + padfill merged (grid = PSLOT/256) ----------------
// scatter: block-aggregated LDS rank + one padded atomic per expert (real slots)
// padfill: tok_of = 0 for pad/dead slots (addresses provably disjoint from scatter writes)
__global__ __launch_bounds__(256) void scatter_kernel(const int* __restrict__ eid, int* __restrict__ cursor,
                                                      const int* __restrict__ counts, const int* __restrict__ offs,
                                                      const int* __restrict__ mbe,
                                                      int* __restrict__ tok_of, int* __restrict__ pos_of){
    __shared__ int lh[NE];
    __shared__ int base[NE];
    int t = threadIdx.x;
    if (t < NE) lh[t] = 0;
    __syncthreads();
    int i = blockIdx.x*256 + t;
    int e = 0, r = 0;
    if (i < NSLOT){
        e = eid[i];
        if (e < 0) e = 0; if (e > 7) e = 7;
        r = atomicAdd(&lh[e], 1);          // rank within block for this expert
    }
    __syncthreads();
    if (t < NE) base[t] = (lh[t] > 0) ? atomicAdd(&cursor[t*16], lh[t]) : 0;
    __syncthreads();
    if (i < NSLOT){
        int p = base[e] + r;
        if (p < 0) p = 0; if (p >= PSLOT) p = PSLOT - 1;
        tok_of[p] = i >> 1;
        pos_of[i] = p;
    }
    // padfill part: p = i in [0, PSLOT)
    int p = i;
    int pe = mbe[p >> 7];
    if (pe < 0){ tok_of[p] = 0; }
    else if (p >= offs[pe] + counts[pe*16]){ tok_of[p] = 0; }
}

// ---------------- x fp32 -> bf16 (+ control init in block 0) ----------------
__global__ __launch_bounds__(256) void cvtx_kernel(const float* __restrict__ x, u16* __restrict__ xb,
                                                   int* __restrict__ counts, int* __restrict__ cursor){
    if (blockIdx.x == 0 && threadIdx.x < 128){ counts[threadIdx.x] = 0; cursor[threadIdx.x] = 0; }
    int i = (blockIdx.x*256 + threadIdx.x)*8;
    *(short8*)&xb[i] = ldcvt8f(&x[i]);
}

// ---------------- W fp32 [e][K][N] -> bf16 fragment order [e][ntile][kblk][lane*8] ----------------
__global__ __launch_bounds__(256) void cvtshuf_kernel(const float* __restrict__ W, u16* __restrict__ Ws,
                                                      int Kd, int Nd){
    int kbn = Kd >> 5;
    int kb = blockIdx.x % kbn;
    int nb = blockIdx.x / kbn;
    int e  = blockIdx.y;
    const float* Wp = W + (size_t)e * Kd * Nd;
    u16* Wsp       = Ws + (size_t)e * Kd * Nd;
    int t = threadIdx.x;
    __shared__ u16 sh[32*136];
#pragma unroll
    for (int i = 0; i < 2; i++){
        int c = t + 256*i;
        int k = c >> 4, nc = c & 15;
        *(short8*)&sh[k*136 + nc*8] = ldcvt8f(&Wp[(size_t)(kb*32 + k)*Nd + nb*128 + nc*8]);
    }
    __syncthreads();
    int w = t >> 6, l = t & 63;
#pragma unroll
    for (int o = 0; o < 2; o++){
        int nt = 2*w + o;
        int n = nt*16 + (l & 15);
        short8 v;
#pragma unroll
        for (int j = 0; j < 8; j++) v[j] = (short)sh[((l >> 4)*8 + j)*136 + n];
        *(short8*)&Wsp[(size_t)(((nb*8 + nt) * kbn + kb) * 512) + l*8] = v;
    }
}

// ---------------- GEMM1: h = relu(x[tok] @ W1[e] + b1[e]) ----------------
// 2-phase pipeline: B(t+1) prefetched into Bs[c^1] before compute(t); As single-buffered,
// rewritten after the post-compute barrier (vmcnt already drained there -> cheap 2nd barrier).
__global__ __launch_bounds__(256) void gemm1u_kernel(const u16* __restrict__ xb, const int* __restrict__ tok_of,
                                                     const int* __restrict__ mbe, const u16* __restrict__ W1s,
                                                     const float* __restrict__ b1, u16* __restrict__ h){
    const int KB = DM/32;     // 24 kblks
    const int KB2 = DM/64;    // 12 double-steps
    int bid = blockIdx.x;
    int by = bid % 24, mb = bid / 24;   // XCD = bid%8 = by%8 -> B strips L2-local per XCD
    int e = mbe[mb];
    if (e < 0) return;
    int m0 = mb*128, n0 = by*128;

    int t = threadIdx.x;
    int w = t >> 6, l = t & 63;
    int wm = w & 1, wn = w >> 1;

    __shared__ u16 As[128*72];        // 18 KB, single buffer
    __shared__ u16 Bs[2*2*8*512];     // 32 KB: [buf][ks][ntile][lane*8]

    int row0 = t >> 2, kc = t & 3;
    const u16* a0 = xb + (size_t)tok_of[m0 + row0]*DM + kc*8;
    const u16* a1 = xb + (size_t)tok_of[m0 + row0 + 64]*DM + kc*8;
    u16* as0 = &As[row0*72 + kc*8];
    u16* as1 = &As[(row0 + 64)*72 + kc*8];

    const u16* bbase = W1s + (size_t)e*DM*DF + (size_t)(((n0 >> 4) + 2*w)*KB)*512 + l*8;

    f32x4 acc[4][4];
#pragma unroll
    for (int i = 0; i < 4; i++)
#pragma unroll
        for (int j = 0; j < 4; j++) acc[i][j] = (f32x4){0.f,0.f,0.f,0.f};

    // prologue: A(0) -> As, B(0) -> Bs[buf 0]
    {
        short8 p0 = *(const short8*)a0;
        short8 p1 = *(const short8*)(a0 + 32);
        short8 p2 = *(const short8*)a1;
        short8 p3 = *(const short8*)(a1 + 32);
        *(short8*)as0 = p0; *(short8*)(as0 + 32) = p1;
        *(short8*)as1 = p2; *(short8*)(as1 + 32) = p3;
        GLDS16(bbase,                            &Bs[(2*w)*512]);
        GLDS16(bbase + 512,                      &Bs[4096 + (2*w)*512]);
        GLDS16(bbase + (size_t)KB*512,           &Bs[(2*w+1)*512]);
        GLDS16(bbase + (size_t)KB*512 + 512,     &Bs[4096 + (2*w+1)*512]);
    }
    __syncthreads();

    int c = 0;
    short8 av0a, av0b, av1a, av1b;
    for (int kb2 = 0; kb2 < KB2; kb2++){
        if (kb2 + 1 < KB2){
            // prefetch next B tile into the other buffer (flies over the MFMA phase)
            GLDS16(bbase + (size_t)(2*kb2+2)*512,                     &Bs[(c^1)*8192 + (2*w)*512]);
            GLDS16(bbase + (size_t)(2*kb2+3)*512,                     &Bs[(c^1)*8192 + 4096 + (2*w)*512]);
            GLDS16(bbase + (size_t)KB*512 + (size_t)(2*kb2+2)*512,    &Bs[(c^1)*8192 + (2*w+1)*512]);
            GLDS16(bbase + (size_t)KB*512 + (size_t)(2*kb2+3)*512,    &Bs[(c^1)*8192 + 4096 + (2*w+1)*512]);
            av0a = *(const short8*)(a0 + (kb2+1)*64);
            av0b = *(const short8*)(a0 + (kb2+1)*64 + 32);
            av1a = *(const short8*)(a1 + (kb2+1)*64);
            av1b = *(const short8*)(a1 + (kb2+1)*64 + 32);
        }
#pragma unroll
        for (int ks = 0; ks < 2; ks++){
            short8 af[4], bf[4];
#pragma unroll
            for (int mt = 0; mt < 4; mt++)
                af[mt] = *(const short8*)&As[(wm*64 + mt*16 + (l & 15))*72 + ks*32 + (l >> 4)*8];
#pragma unroll
            for (int nt = 0; nt < 4; nt++)
                bf[nt] = *(const short8*)&Bs[c*8192 + ks*4096 + (wn*4 + nt)*512 + l*8];
#pragma unroll
            for (int mt = 0; mt < 4; mt++)
#pragma unroll
                for (int nt = 0; nt < 4; nt++)
                    acc[mt][nt] = __builtin_amdgcn_mfma_f32_16x16x32_bf16(af[mt], bf[nt], acc[mt][nt], 0, 0, 0);
        }
        __syncthreads();   // drains B(t+1)/A(t+1) loads (overlapped with MFMA) + fences As reads
        if (kb2 + 1 < KB2){
            *(short8*)as0 = av0a; *(short8*)(as0 + 32) = av0b;
            *(short8*)as1 = av1a; *(short8*)(as1 + 32) = av1b;
            __syncthreads();   // nothing outstanding on vmcnt here -> cheap
        }
        c ^= 1;
    }

#pragma unroll
    for (int nt = 0; nt < 4; nt++){
        int col = n0 + wn*64 + nt*16 + (l & 15);
        float bv = b1[e*DF + col];
#pragma unroll
        for (int mt = 0; mt < 4; mt++){
#pragma unroll
            for (int r = 0; r < 4; r++){
                int grow = m0 + wm*64 + mt*16 + (l >> 4)*4 + r;
                float v = acc[mt][nt][r] + bv;
                v = v > 0.f ? v : 0.f;
                h[(size_t)grow*DF + col] = f2b(v);
            }
        }
    }
}

// ---------------- GEMM2: y[slot] = h[slot] @ W2[e] + b2[e]  (64x128 tiles, 864 blocks) ----------------
// Per-wave 32x64 (acc[2][4]); grid = 6*MB64; XCD = bid%8 = mb%8 -> 6 blocks sharing an h-panel
// stay on one XCD (L2-local A).
__global__ __launch_bounds__(256) void gemm2u_kernel(const u16* __restrict__ h, const int* __restrict__ mbe,
                                                     const u16* __restrict__ W2s, const float* __restrict__ b2,
                                                     float* __restrict__ y){
    const int KB = DF/32;     // 96 kblks
    const int KB2 = DF/64;    // 48 double-steps
    int bid = blockIdx.x;
    int mb = bid % MB64;      // 0..143
    int by = bid / MB64;      // 0..5
    int e = mbe[mb >> 1];
    if (e < 0) return;
    int m0 = mb*64, n0 = by*128;

    int t = threadIdx.x;
    int w = t >> 6, l = t & 63;
    int wm = w & 1, wn = w >> 1;

    __shared__ u16 As[64*72];         // 9 KB
    __shared__ u16 Bs[2*2*8*512];     // 32 KB

    int row0 = t >> 2, kc = t & 3;
    const u16* a0 = h + (size_t)(m0 + row0)*DF + kc*8;
    u16* as0 = &As[row0*72 + kc*8];

    const u16* bbase = W2s + (size_t)e*DF*DM + (size_t)(((n0 >> 4) + 2*w)*KB)*512 + l*8;

    f32x4 acc[2][4];
#pragma unroll
    for (int i = 0; i < 2; i++)
#pragma unroll
        for (int j = 0; j < 4; j++) acc[i][j] = (f32x4){0.f,0.f,0.f,0.f};

    {
        short8 p0 = *(const short8*)a0;
        short8 p1 = *(const short8*)(a0 + 32);
        *(short8*)as0 = p0; *(short8*)(as0 + 32) = p1;
        GLDS16(bbase,                            &Bs[(2*w)*512]);
        GLDS16(bbase + 512,                      &Bs[4096 + (2*w)*512]);
        GLDS16(bbase + (size_t)KB*512,           &Bs[(2*w+1)*512]);
        GLDS16(bbase + (size_t)KB*512 + 512,     &Bs[4096 + (2*w+1)*512]);
    }
    __syncthreads();

    int c = 0;
    short8 av0a, av0b;
    for (int kb2 = 0; kb2 < KB2; kb2++){
        if (kb2 + 1 < KB2){
            GLDS16(bbase + (size_t)(2*kb2+2)*512,                     &Bs[(c^1)*8192 + (2*w)*512]);
            GLDS16(bbase + (size_t)(2*kb2+3)*512,                     &Bs[(c^1)*8192 + 4096 + (2*w)*512]);
            GLDS16(bbase + (size_t)KB*512 + (size_t)(2*kb2+2)*512,    &Bs[(c^1)*8192 + (2*w+1)*512]);
            GLDS16(bbase + (size_t)KB*512 + (size_t)(2*kb2+3)*512,    &Bs[(c^1)*8192 + 4096 + (2*w+1)*512]);
            av0a = *(const short8*)(a0 + (kb2+1)*64);
            av0b = *(const short8*)(a0 + (kb2+1)*64 + 32);
        }
#pragma unroll
        for (int ks = 0; ks < 2; ks++){
            short8 af[2], bf[4];
#pragma unroll
            for (int mt = 0; mt < 2; mt++)
                af[mt] = *(const short8*)&As[(wm*32 + mt*16 + (l & 15))*72 + ks*32 + (l >> 4)*8];
#pragma unroll
            for (int nt = 0; nt < 4; nt++)
                bf[nt] = *(const short8*)&Bs[c*8192 + ks*4096 + (wn*4 + nt)*512 + l*8];
#pragma unroll
            for (int mt = 0; mt < 2; mt++)
#pragma unroll
                for (int nt = 0; nt < 4; nt++)
                    acc[mt][nt] = __builtin_amdgcn_mfma_f32_16x16x32_bf16(af[mt], bf[nt], acc[mt][nt], 0, 0, 0);
        }
        __syncthreads();
        if (kb2 + 1 < KB2){
            *(short8*)as0 = av0a; *(short8*)(as0 + 32) = av0b;
            __syncthreads();
        }
        c ^= 1;
    }

#pragma unroll
    for (int nt = 0; nt < 4; nt++){
        int col = n0 + wn*64 + nt*16 + (l & 15);
        float bv = b2[e*DM + col];
#pragma unroll
        for (int mt = 0; mt < 2; mt++){
#pragma unroll
            for (int r = 0; r < 4; r++){
                int grow = m0 + wm*32 + mt*16 + (l >> 4)*4 + r;
                y[(size_t)grow*DM + col] = acc[mt][nt][r] + bv;
            }
        }
    }
}

// ---------------- combine: out[s] = w0*y[pos(s,0)] + w1*y[pos(s,1)] ----------------
__global__ __launch_bounds__(256) void combine_kernel(const float* __restrict__ y, const int* __restrict__ pos_of,
                                                      const float* __restrict__ gw, float* __restrict__ out){
    int i = blockIdx.x*256 + threadIdx.x;   // float4 index
    int s = i / (DM/4);
    int c4 = (i - s*(DM/4))*4;
    int p0 = pos_of[2*s], p1 = pos_of[2*s+1];
    float w0 = gw[2*s], w1 = gw[2*s+1];
    float4 a = *(const float4*)&y[(size_t)p0*DM + c4];
    float4 b = *(const float4*)&y[(size_t)p1*DM + c4];
    float4 o;
    o.x = w0*a.x + w1*b.x;
    o.y = w0*a.y + w1*b.y;
    o.z = w0*a.z + w1*b.z;
    o.w = w0*a.w + w1*b.w;
    *(float4*)&out[(size_t)s*DM + c4] = o;
}

// ---------------- zero-workspace fallback ----------------
__global__ __launch_bounds__(256) void fallback_kernel(const float* __restrict__ x, const float* __restrict__ Wg,
                                                       const float* __restrict__ W1, const float* __restrict__ b1,
                                                       const float* __restrict__ W2, const float* __restrict__ b2,
                                                       float* __restrict__ out){
    int s = blockIdx.x;
    int t = threadIdx.x;
    __shared__ float xr[DM];
    __shared__ float hl[DF];
    __shared__ float yl[DM];
    __shared__ float lacc[4*NE];
    __shared__ int   sel_e[2];
    __shared__ float sel_w[2];

    for (int i = t; i < DM; i += 256){ xr[i] = x[(size_t)s*DM + i]; yl[i] = 0.f; }
    __syncthreads();

    float acc[NE];
#pragma unroll
    for (int e = 0; e < NE; e++) acc[e] = 0.f;
    for (int d = t*3; d < t*3 + 3; d++){
        float xv = xr[d];
#pragma unroll
        for (int e = 0; e < NE; e++) acc[e] += xv * Wg[d*NE + e];
    }
#pragma unroll
    for (int e = 0; e < NE; e++){
#pragma unroll
        for (int off = 32; off; off >>= 1) acc[e] += __shfl_down(acc[e], off);
    }
    if ((t & 63) == 0){
        int wv = t >> 6;
#pragma unroll
        for (int e = 0; e < NE; e++) lacc[wv*NE + e] = acc[e];
    }
    __syncthreads();
    if (t == 0){
        float lg[NE];
#pragma unroll
        for (int e = 0; e < NE; e++) lg[e] = lacc[e] + lacc[NE + e] + lacc[2*NE + e] + lacc[3*NE + e];
        int i1 = 0; float v1 = lg[0];
        for (int e = 1; e < NE; e++) if (lg[e] > v1){ v1 = lg[e]; i1 = e; }
        int i2 = -1; float v2 = -1e30f;
        for (int e = 0; e < NE; e++) if (e != i1 && lg[e] > v2){ v2 = lg[e]; i2 = e; }
        if (i2 < 0){ i2 = (i1 + 1) & 7; sel_w[0] = 1.f; sel_w[1] = 0.f; }
        else {
            float e2 = expf(v2 - v1);
            sel_w[0] = 1.f / (1.f + e2);
            sel_w[1] = e2 / (1.f + e2);
        }
        sel_e[0] = i1; sel_e[1] = i2;
    }
    __syncthreads();

    for (int kk = 0; kk < 2; kk++){
        int e = sel_e[kk];
        float wgt = sel_w[kk];
        const float* w1p = W1 + (size_t)e * DM * DF;
        for (int j = t; j < DF; j += 256){
            float a = b1[e*DF + j];
            for (int k = 0; k < DM; k++) a += xr[k] * w1p[(size_t)k*DF + j];
            hl[j] = a > 0.f ? a : 0.f;
        }
        __syncthreads();
        const float* w2p = W2 + (size_t)e * DF * DM;
        for (int c = t; c < DM; c += 256){
            float a = b2[e*DM + c];
            for (int k = 0; k < DF; k++) a += hl[k] * w2p[(size_t)k*DM + c];
            yl[c] += wgt * a;
        }
        __syncthreads();
    }
    for (int c = t; c < DM; c += 256) out[(size_t)s*DM + c] = yl[c];
}

extern "C" void kernel_launch(void* const* d_in, const int* in_sizes, int n_in,
                              void* d_out, int out_size, void* d_ws, size_t ws_size,
                              hipStream_t stream) {
    const float* x  = (const float*)d_in[0];
    const float* Wg = (const float*)d_in[1];
    const float* W1 = (const float*)d_in[2];
    const float* b1 = (const float*)d_in[3];
    const float* W2 = (const float*)d_in[4];
    const float* b2 = (const float*)d_in[5];
    float* out = (float*)d_out;

    char* ws = (char*)d_ws;
    int*   counts = (int*)(ws + WS_COUNTS);
    int*   cursor = (int*)(ws + WS_CURSOR);
    int*   offs   = (int*)(ws + WS_OFFS);
    int*   mbe    = (int*)(ws + WS_MBE);
    int*   eid    = (int*)(ws + WS_EID);
    float* gw     = (float*)(ws + WS_GW);
    int*   pos_of = (int*)(ws + WS_POS);
    int*   tok_of = (int*)(ws + WS_TOK);

    const size_t xbB = (size_t)S_TOK*DM*2;           //  6.29 MB
    const size_t wB  = (size_t)NE*DM*DF*2;           // 37.75 MB each
    const size_t hB  = (size_t)PSLOT*DF*2;           // 56.62 MB
    const size_t need = CTRL_BYTES + xbB + 2*wB + hB;  // 138.7 MB

    if (ws_size < need){
        fallback_kernel<<<S_TOK, 256, 0, stream>>>(x, Wg, W1, b1, W2, b2, out);
        return;
    }

    u16* xb  = (u16*)(ws + CTRL_BYTES);
    u16* W1s = (u16*)(ws + CTRL_BYTES + xbB);
    u16* W2s = (u16*)(ws + CTRL_BYTES + xbB + wB);
    u16* h   = (u16*)(ws + CTRL_BYTES + xbB + 2*wB);
    // y (28.3 MB fp32) reuses the W1s region (37.75 MB) — W1s is dead once gemm1 completes,
    // and the next graph replay rewrites W1s via cvtshuf before gemm1 reads it again.
    float* yb = (float*)(ws + CTRL_BYTES + xbB);

    cvtx_kernel<<<S_TOK*DM/8/256, 256, 0, stream>>>(x, xb, counts, cursor);
    cvtshuf_kernel<<<dim3((DM/32)*(DF/128), NE), 256, 0, stream>>>(W1, W1s, DM, DF);
    cvtshuf_kernel<<<dim3((DF/32)*(DM/128), NE), 256, 0, stream>>>(W2, W2s, DF, DM);
    gate_kernel<<<GATE_BLOCKS, 256, 0, stream>>>(x, Wg, eid, gw, counts);
    offsets_kernel<<<1, 1, 0, stream>>>(counts, offs, cursor, mbe);
    scatter_kernel<<<PSLOT/256, 256, 0, stream>>>(eid, cursor, counts, offs, mbe, tok_of, pos_of);

    gemm1u_kernel<<<MBMAX*24, 256, 0, stream>>>(xb, tok_of, mbe, W1s, b1, h);
    gemm2u_kernel<<<6*MB64, 256, 0, stream>>>(h, mbe, W2s, b2, yb);
    combine_kernel<<<(S_TOK*(DM/4))/256, 256, 0, stream>>>(yb, pos_of, gw, out);
}

// Round 7
// 345.708 us; speedup vs baseline: 1.1064x; 1.1064x over previous
//
#include <hip/hip_runtime.h>
#include <math.h>

typedef short short8 __attribute__((ext_vector_type(8)));
typedef float f32x4 __attribute__((ext_vector_type(4)));
typedef unsigned short u16;
typedef unsigned int u32;

#define S_TOK 4096
#define DM 768
#define DF 3072
#define NE 8
#define NSLOT (S_TOK*2)      // 8192 real slots
#define PSLOT 9216           // padded capacity (8192 + 8*127 rounded up)
#define MBMAX 72             // PSLOT/128

// ---- control block ----
// counts/cursor are cacheline-padded: expert e lives at [e*16] (64 B stride)
#define WS_COUNTS   0        // 128 ints (8 x 16-int stride)
#define WS_CURSOR   512      // 128 ints
#define WS_OFFS     1024     // 9 ints (padded expert starts)
#define WS_MBE      1088     // MBMAX ints (mb -> expert, -1 = dead)
#define WS_EID      2048     // NSLOT ints
#define WS_GW       (WS_EID + NSLOT*4)
#define WS_POS      (WS_GW  + NSLOT*4)      // NSLOT ints: slot position of (token,k)
#define WS_TOK      (WS_POS + NSLOT*4)      // PSLOT ints
#define CTRL_BYTES  262144

#define AS1 __attribute__((address_space(1)))
#define AS3 __attribute__((address_space(3)))
#define GLDS16(g, s) __builtin_amdgcn_global_load_lds((const AS1 u32*)(g), (AS3 u32*)(s), 16, 0, 0)

__device__ inline u16 f2b(float f){
    u32 u = __builtin_bit_cast(u32, f);
    u32 r = (u + 0x7fffu + ((u >> 16) & 1u)) >> 16;   // RNE
    return (u16)r;
}
__device__ inline short8 ldcvt8f(const float* p){
    float4 a = *(const float4*)p;
    float4 b = *(const float4*)(p + 4);
    short8 v;
    v[0]=(short)f2b(a.x); v[1]=(short)f2b(a.y); v[2]=(short)f2b(a.z); v[3]=(short)f2b(a.w);
    v[4]=(short)f2b(b.x); v[5]=(short)f2b(b.y); v[6]=(short)f2b(b.z); v[7]=(short)f2b(b.w);
    return v;
}

// ---------------- gate: grid-stride waves + LDS histogram + padded atomics ----------------
#define GATE_BLOCKS 128
__global__ __launch_bounds__(256) void gate_kernel(const float* __restrict__ x, const float* __restrict__ Wg,
                                                   int* __restrict__ eid, float* __restrict__ gw,
                                                   int* __restrict__ counts){
    __shared__ int lh[NE];
    int t = threadIdx.x;
    if (t < NE) lh[t] = 0;
    __syncthreads();
    int wv = t >> 6, l = t & 63;
    int wgid = blockIdx.x*4 + wv;            // 0 .. GATE_BLOCKS*4-1
    const int NW = GATE_BLOCKS*4;

    for (int s = wgid; s < S_TOK; s += NW){
        float acc[NE];
#pragma unroll
        for (int e = 0; e < NE; e++) acc[e] = 0.f;
        const float* xr = x + (size_t)s * DM;
#pragma unroll
        for (int i = 0; i < DM/64; i++){
            int d = l + 64*i;
            float xv = xr[d];
            float4 w0 = *(const float4*)(Wg + d*NE);
            float4 w1 = *(const float4*)(Wg + d*NE + 4);
            acc[0] += xv*w0.x; acc[1] += xv*w0.y; acc[2] += xv*w0.z; acc[3] += xv*w0.w;
            acc[4] += xv*w1.x; acc[5] += xv*w1.y; acc[6] += xv*w1.z; acc[7] += xv*w1.w;
        }
#pragma unroll
        for (int e = 0; e < NE; e++){
#pragma unroll
            for (int off = 32; off; off >>= 1) acc[e] += __shfl_down(acc[e], off);
        }
        if (l == 0){
            int i1 = 0; float v1 = acc[0];
            for (int e = 1; e < NE; e++) if (acc[e] > v1){ v1 = acc[e]; i1 = e; }
            int i2 = -1; float v2 = -1e30f;
            for (int e = 0; e < NE; e++) if (e != i1 && acc[e] > v2){ v2 = acc[e]; i2 = e; }
            float w0, w1;
            if (i2 < 0){ i2 = (i1 + 1) & 7; w0 = 1.f; w1 = 0.f; }
            else {
                float e2 = expf(v2 - v1);
                w0 = 1.f / (1.f + e2);
                w1 = e2 / (1.f + e2);
            }
            eid[2*s]   = i1; gw[2*s]   = w0;
            eid[2*s+1] = i2; gw[2*s+1] = w1;
            atomicAdd(&lh[i1], 1);
            atomicAdd(&lh[i2], 1);
        }
    }
    __syncthreads();
    if (t < NE && lh[t] > 0) atomicAdd(&counts[t*16], lh[t]);
}

// ---------------- offsets with capacity padding + mb->expert map ----------------
__global__ void offsets_kernel(const int* __restrict__ counts, int* __restrict__ offs,
                               int* __restrict__ cursor, int* __restrict__ mbe){
    if (threadIdx.x == 0 && blockIdx.x == 0){
        int P = 0;
        for (int e = 0; e < NE; e++){
            offs[e] = P; cursor[e*16] = P;
            int padded = ((counts[e*16] + 127) >> 7) << 7;
            for (int mb = P >> 7; mb < (P + padded) >> 7; mb++) mbe[mb] = e;
            P += padded;
        }
        offs[NE] = P;
        for (int mb = P >> 7; mb < MBMAX; mb++) mbe[mb] = -1;
    }
}

// ---------------- scatter + padfill merged (grid = PSLOT/256) ----------------
__global__ __launch_bounds__(256) void scatter_kernel(const int* __restrict__ eid, int* __restrict__ cursor,
                                                      const int* __restrict__ counts, const int* __restrict__ offs,
                                                      const int* __restrict__ mbe,
                                                      int* __restrict__ tok_of, int* __restrict__ pos_of){
    __shared__ int lh[NE];
    __shared__ int base[NE];
    int t = threadIdx.x;
    if (t < NE) lh[t] = 0;
    __syncthreads();
    int i = blockIdx.x*256 + t;
    int e = 0, r = 0;
    if (i < NSLOT){
        e = eid[i];
        if (e < 0) e = 0; if (e > 7) e = 7;
        r = atomicAdd(&lh[e], 1);          // rank within block for this expert
    }
    __syncthreads();
    if (t < NE) base[t] = (lh[t] > 0) ? atomicAdd(&cursor[t*16], lh[t]) : 0;
    __syncthreads();
    if (i < NSLOT){
        int p = base[e] + r;
        if (p < 0) p = 0; if (p >= PSLOT) p = PSLOT - 1;
        tok_of[p] = i >> 1;
        pos_of[i] = p;
    }
    // padfill part: p = i in [0, PSLOT)
    int p = i;
    int pe = mbe[p >> 7];
    if (pe < 0){ tok_of[p] = 0; }
    else if (p >= offs[pe] + counts[pe*16]){ tok_of[p] = 0; }
}

// ---------------- x fp32 -> bf16 (+ control init in block 0) ----------------
__global__ __launch_bounds__(256) void cvtx_kernel(const float* __restrict__ x, u16* __restrict__ xb,
                                                   int* __restrict__ counts, int* __restrict__ cursor){
    if (blockIdx.x == 0 && threadIdx.x < 128){ counts[threadIdx.x] = 0; cursor[threadIdx.x] = 0; }
    int i = (blockIdx.x*256 + threadIdx.x)*8;
    *(short8*)&xb[i] = ldcvt8f(&x[i]);
}

// ---------------- W fp32 [e][K][N] -> bf16 fragment order [e][ntile][kblk][lane*8] ----------------
__global__ __launch_bounds__(256) void cvtshuf_kernel(const float* __restrict__ W, u16* __restrict__ Ws,
                                                      int Kd, int Nd){
    int kbn = Kd >> 5;
    int kb = blockIdx.x % kbn;
    int nb = blockIdx.x / kbn;
    int e  = blockIdx.y;
    const float* Wp = W + (size_t)e * Kd * Nd;
    u16* Wsp       = Ws + (size_t)e * Kd * Nd;
    int t = threadIdx.x;
    __shared__ u16 sh[32*136];
#pragma unroll
    for (int i = 0; i < 2; i++){
        int c = t + 256*i;
        int k = c >> 4, nc = c & 15;
        *(short8*)&sh[k*136 + nc*8] = ldcvt8f(&Wp[(size_t)(kb*32 + k)*Nd + nb*128 + nc*8]);
    }
    __syncthreads();
    int w = t >> 6, l = t & 63;
#pragma unroll
    for (int o = 0; o < 2; o++){
        int nt = 2*w + o;
        int n = nt*16 + (l & 15);
        short8 v;
#pragma unroll
        for (int j = 0; j < 8; j++) v[j] = (short)sh[((l >> 4)*8 + j)*136 + n];
        *(short8*)&Wsp[(size_t)(((nb*8 + nt) * kbn + kb) * 512) + l*8] = v;
    }
}

// ---------------- GEMM1: h = relu(x[tok] @ W1[e] + b1[e]) ----------------
// 2-phase pipeline (unchanged, known-good): B(t+1) into Bs[c^1] before compute(t).
__global__ __launch_bounds__(256) void gemm1u_kernel(const u16* __restrict__ xb, const int* __restrict__ tok_of,
                                                     const int* __restrict__ mbe, const u16* __restrict__ W1s,
                                                     const float* __restrict__ b1, u16* __restrict__ h){
    const int KB = DM/32;     // 24 kblks
    const int KB2 = DM/64;    // 12 double-steps
    int bid = blockIdx.x;
    int by = bid % 24, mb = bid / 24;   // XCD = bid%8 = by%8 -> B strips L2-local per XCD
    int e = mbe[mb];
    if (e < 0) return;
    int m0 = mb*128, n0 = by*128;

    int t = threadIdx.x;
    int w = t >> 6, l = t & 63;
    int wm = w & 1, wn = w >> 1;

    __shared__ u16 As[128*72];        // 18 KB, single buffer
    __shared__ u16 Bs[2*2*8*512];     // 32 KB: [buf][ks][ntile][lane*8]

    int row0 = t >> 2, kc = t & 3;
    const u16* a0 = xb + (size_t)tok_of[m0 + row0]*DM + kc*8;
    const u16* a1 = xb + (size_t)tok_of[m0 + row0 + 64]*DM + kc*8;
    u16* as0 = &As[row0*72 + kc*8];
    u16* as1 = &As[(row0 + 64)*72 + kc*8];

    const u16* bbase = W1s + (size_t)e*DM*DF + (size_t)(((n0 >> 4) + 2*w)*KB)*512 + l*8;

    f32x4 acc[4][4];
#pragma unroll
    for (int i = 0; i < 4; i++)
#pragma unroll
        for (int j = 0; j < 4; j++) acc[i][j] = (f32x4){0.f,0.f,0.f,0.f};

    {
        short8 p0 = *(const short8*)a0;
        short8 p1 = *(const short8*)(a0 + 32);
        short8 p2 = *(const short8*)a1;
        short8 p3 = *(const short8*)(a1 + 32);
        *(short8*)as0 = p0; *(short8*)(as0 + 32) = p1;
        *(short8*)as1 = p2; *(short8*)(as1 + 32) = p3;
        GLDS16(bbase,                            &Bs[(2*w)*512]);
        GLDS16(bbase + 512,                      &Bs[4096 + (2*w)*512]);
        GLDS16(bbase + (size_t)KB*512,           &Bs[(2*w+1)*512]);
        GLDS16(bbase + (size_t)KB*512 + 512,     &Bs[4096 + (2*w+1)*512]);
    }
    __syncthreads();

    int c = 0;
    short8 av0a, av0b, av1a, av1b;
    for (int kb2 = 0; kb2 < KB2; kb2++){
        if (kb2 + 1 < KB2){
            GLDS16(bbase + (size_t)(2*kb2+2)*512,                     &Bs[(c^1)*8192 + (2*w)*512]);
            GLDS16(bbase + (size_t)(2*kb2+3)*512,                     &Bs[(c^1)*8192 + 4096 + (2*w)*512]);
            GLDS16(bbase + (size_t)KB*512 + (size_t)(2*kb2+2)*512,    &Bs[(c^1)*8192 + (2*w+1)*512]);
            GLDS16(bbase + (size_t)KB*512 + (size_t)(2*kb2+3)*512,    &Bs[(c^1)*8192 + 4096 + (2*w+1)*512]);
            av0a = *(const short8*)(a0 + (kb2+1)*64);
            av0b = *(const short8*)(a0 + (kb2+1)*64 + 32);
            av1a = *(const short8*)(a1 + (kb2+1)*64);
            av1b = *(const short8*)(a1 + (kb2+1)*64 + 32);
        }
#pragma unroll
        for (int ks = 0; ks < 2; ks++){
            short8 af[4], bf[4];
#pragma unroll
            for (int mt = 0; mt < 4; mt++)
                af[mt] = *(const short8*)&As[(wm*64 + mt*16 + (l & 15))*72 + ks*32 + (l >> 4)*8];
#pragma unroll
            for (int nt = 0; nt < 4; nt++)
                bf[nt] = *(const short8*)&Bs[c*8192 + ks*4096 + (wn*4 + nt)*512 + l*8];
#pragma unroll
            for (int mt = 0; mt < 4; mt++)
#pragma unroll
                for (int nt = 0; nt < 4; nt++)
                    acc[mt][nt] = __builtin_amdgcn_mfma_f32_16x16x32_bf16(af[mt], bf[nt], acc[mt][nt], 0, 0, 0);
        }
        __syncthreads();
        if (kb2 + 1 < KB2){
            *(short8*)as0 = av0a; *(short8*)(as0 + 32) = av0b;
            *(short8*)as1 = av1a; *(short8*)(as1 + 32) = av1b;
            __syncthreads();
        }
        c ^= 1;
    }

#pragma unroll
    for (int nt = 0; nt < 4; nt++){
        int col = n0 + wn*64 + nt*16 + (l & 15);
        float bv = b1[e*DF + col];
#pragma unroll
        for (int mt = 0; mt < 4; mt++){
#pragma unroll
            for (int r = 0; r < 4; r++){
                int grow = m0 + wm*64 + mt*16 + (l >> 4)*4 + r;
                float v = acc[mt][nt][r] + bv;
                v = v > 0.f ? v : 0.f;
                h[(size_t)grow*DF + col] = f2b(v);
            }
        }
    }
}

// ---------------- GEMM2: y[slot] = h[slot] @ W2[e] + b2[e] ----------------
// 128x128 tile, counted-vmcnt 3-buffer pipeline (T3/T4): B(t+2) issued at step t stays in
// flight across raw s_barriers; s_waitcnt vmcnt(4) guarantees B(t+1)+A-regs landed.
// FIXED (r5): A-prefetch guard kt+2 < NT (was kt+3 -> last K-tile used stale A rows).
__global__ __launch_bounds__(256) void gemm2p_kernel(const u16* __restrict__ h, const int* __restrict__ mbe,
                                                     const u16* __restrict__ W2s, const float* __restrict__ b2,
                                                     float* __restrict__ y){
    const int KB = DF/32;     // 96 kblks
    const int NT = DF/64;     // 48 double-steps
    int bid = blockIdx.x;
    int mb = bid % MBMAX;     // XCD = bid%8 = mb%8 -> A rows (h) L2-local per XCD
    int by = bid / MBMAX;     // 0..5
    int e = mbe[mb];
    if (e < 0) return;
    int m0 = mb*128, n0 = by*128;

    int t = threadIdx.x;
    int w = t >> 6, l = t & 63;
    int wm = w & 1, wn = w >> 1;

    __shared__ u16 As[128*72];        // 18 KB
    __shared__ u16 Bs[3*2*8*512];     // 48 KB: [buf][ks][ntile][lane*8]

    int row0 = t >> 2, kc = t & 3;
    const u16* a0 = h + (size_t)(m0 + row0)*DF + kc*8;
    const u16* a1 = h + (size_t)(m0 + row0 + 64)*DF + kc*8;
    u16* as0 = &As[row0*72 + kc*8];
    u16* as1 = &As[(row0 + 64)*72 + kc*8];

    const u16* bbase = W2s + (size_t)e*DF*DM + (size_t)(((n0 >> 4) + 2*w)*KB)*512 + l*8;

#define STB2(kb2, buf) do{ \
    GLDS16(bbase + (size_t)(2*(kb2))*512,                   &Bs[(buf)*8192 + (2*w)*512]); \
    GLDS16(bbase + (size_t)(2*(kb2)+1)*512,                 &Bs[(buf)*8192 + 4096 + (2*w)*512]); \
    GLDS16(bbase + (size_t)KB*512 + (size_t)(2*(kb2))*512,  &Bs[(buf)*8192 + (2*w+1)*512]); \
    GLDS16(bbase + (size_t)KB*512 + (size_t)(2*(kb2)+1)*512,&Bs[(buf)*8192 + 4096 + (2*w+1)*512]); \
}while(0)

    f32x4 acc[4][4];
#pragma unroll
    for (int i = 0; i < 4; i++)
#pragma unroll
        for (int j = 0; j < 4; j++) acc[i][j] = (f32x4){0.f,0.f,0.f,0.f};

    // prologue: A(0)->regs, G(0)->buf0, G(1)->buf1, As<-A(0), A(1)->regs
    short8 av0a = *(const short8*)a0;
    short8 av0b = *(const short8*)(a0 + 32);
    short8 av1a = *(const short8*)a1;
    short8 av1b = *(const short8*)(a1 + 32);
    STB2(0, 0);
    STB2(1, 1);
    *(short8*)as0 = av0a; *(short8*)(as0 + 32) = av0b;   // compiler waits A(0) regs only
    *(short8*)as1 = av1a; *(short8*)(as1 + 32) = av1b;
    av0a = *(const short8*)(a0 + 64);
    av0b = *(const short8*)(a0 + 96);
    av1a = *(const short8*)(a1 + 64);
    av1b = *(const short8*)(a1 + 96);
    // outstanding: G0(4,oldest), G1(4), A1(4,newest) -> vmcnt(8): G0 landed
    __builtin_amdgcn_sched_barrier(0);
    asm volatile("s_waitcnt vmcnt(8) lgkmcnt(0)" ::: "memory");
    __builtin_amdgcn_sched_barrier(0);
    __builtin_amdgcn_s_barrier();

    int cb = 0, sb = 2;   // compute buf, stage buf (t+2)
    for (int kt = 0; kt < NT; kt++){
        if (kt + 2 < NT) STB2(kt + 2, sb);
#pragma unroll
        for (int ks = 0; ks < 2; ks++){
            short8 af[4], bf[4];
#pragma unroll
            for (int mt = 0; mt < 4; mt++)
                af[mt] = *(const short8*)&As[(wm*64 + mt*16 + (l & 15))*72 + ks*32 + (l >> 4)*8];
#pragma unroll
            for (int nt = 0; nt < 4; nt++)
                bf[nt] = *(const short8*)&Bs[cb*8192 + ks*4096 + (wn*4 + nt)*512 + l*8];
#pragma unroll
            for (int mt = 0; mt < 4; mt++)
#pragma unroll
                for (int nt = 0; nt < 4; nt++)
                    acc[mt][nt] = __builtin_amdgcn_mfma_f32_16x16x32_bf16(af[mt], bf[nt], acc[mt][nt], 0, 0, 0);
        }
        // in-flight: G(t+1) oldest, A(t+1), G(t+2) newest -> vmcnt(4): G(t+1)+A(t+1) done.
        // lgkmcnt(0): this wave's ds_reads complete before others may overwrite As.
        __builtin_amdgcn_sched_barrier(0);
        asm volatile("s_waitcnt vmcnt(4) lgkmcnt(0)" ::: "memory");
        __builtin_amdgcn_sched_barrier(0);
        __builtin_amdgcn_s_barrier();
        if (kt + 1 < NT){
            *(short8*)as0 = av0a; *(short8*)(as0 + 32) = av0b;
            *(short8*)as1 = av1a; *(short8*)(as1 + 32) = av1b;
            if (kt + 2 < NT){
                av0a = *(const short8*)(a0 + (kt+2)*64);
                av0b = *(const short8*)(a0 + (kt+2)*64 + 32);
                av1a = *(const short8*)(a1 + (kt+2)*64);
                av1b = *(const short8*)(a1 + (kt+2)*64 + 32);
            }
            __builtin_amdgcn_sched_barrier(0);
            asm volatile("s_waitcnt lgkmcnt(0)" ::: "memory");
            __builtin_amdgcn_sched_barrier(0);
            __builtin_amdgcn_s_barrier();
        }
        cb = (cb == 2) ? 0 : cb + 1;
        sb = (sb == 2) ? 0 : sb + 1;
    }
#undef STB2

#pragma unroll
    for (int nt = 0; nt < 4; nt++){
        int col = n0 + wn*64 + nt*16 + (l & 15);
        float bv = b2[e*DM + col];
#pragma unroll
        for (int mt = 0; mt < 4; mt++){
#pragma unroll
            for (int r = 0; r < 4; r++){
                int grow = m0 + wm*64 + mt*16 + (l >> 4)*4 + r;
                y[(size_t)grow*DM + col] = acc[mt][nt][r] + bv;
            }
        }
    }
}

// ---------------- combine: out[s] = w0*y[pos(s,0)] + w1*y[pos(s,1)] ----------------
__global__ __launch_bounds__(256) void combine_kernel(const float* __restrict__ y, const int* __restrict__ pos_of,
                                                      const float* __restrict__ gw, float* __restrict__ out){
    int i = blockIdx.x*256 + threadIdx.x;   // float4 index
    int s = i / (DM/4);
    int c4 = (i - s*(DM/4))*4;
    int p0 = pos_of[2*s], p1 = pos_of[2*s+1];
    float w0 = gw[2*s], w1 = gw[2*s+1];
    float4 a = *(const float4*)&y[(size_t)p0*DM + c4];
    float4 b = *(const float4*)&y[(size_t)p1*DM + c4];
    float4 o;
    o.x = w0*a.x + w1*b.x;
    o.y = w0*a.y + w1*b.y;
    o.z = w0*a.z + w1*b.z;
    o.w = w0*a.w + w1*b.w;
    *(float4*)&out[(size_t)s*DM + c4] = o;
}

// ---------------- zero-workspace fallback ----------------
__global__ __launch_bounds__(256) void fallback_kernel(const float* __restrict__ x, const float* __restrict__ Wg,
                                                       const float* __restrict__ W1, const float* __restrict__ b1,
                                                       const float* __restrict__ W2, const float* __restrict__ b2,
                                                       float* __restrict__ out){
    int s = blockIdx.x;
    int t = threadIdx.x;
    __shared__ float xr[DM];
    __shared__ float hl[DF];
    __shared__ float yl[DM];
    __shared__ float lacc[4*NE];
    __shared__ int   sel_e[2];
    __shared__ float sel_w[2];

    for (int i = t; i < DM; i += 256){ xr[i] = x[(size_t)s*DM + i]; yl[i] = 0.f; }
    __syncthreads();

    float acc[NE];
#pragma unroll
    for (int e = 0; e < NE; e++) acc[e] = 0.f;
    for (int d = t*3; d < t*3 + 3; d++){
        float xv = xr[d];
#pragma unroll
        for (int e = 0; e < NE; e++) acc[e] += xv * Wg[d*NE + e];
    }
#pragma unroll
    for (int e = 0; e < NE; e++){
#pragma unroll
        for (int off = 32; off; off >>= 1) acc[e] += __shfl_down(acc[e], off);
    }
    if ((t & 63) == 0){
        int wv = t >> 6;
#pragma unroll
        for (int e = 0; e < NE; e++) lacc[wv*NE + e] = acc[e];
    }
    __syncthreads();
    if (t == 0){
        float lg[NE];
#pragma unroll
        for (int e = 0; e < NE; e++) lg[e] = lacc[e] + lacc[NE + e] + lacc[2*NE + e] + lacc[3*NE + e];
        int i1 = 0; float v1 = lg[0];
        for (int e = 1; e < NE; e++) if (lg[e] > v1){ v1 = lg[e]; i1 = e; }
        int i2 = -1; float v2 = -1e30f;
        for (int e = 0; e < NE; e++) if (e != i1 && lg[e] > v2){ v2 = lg[e]; i2 = e; }
        if (i2 < 0){ i2 = (i1 + 1) & 7; sel_w[0] = 1.f; sel_w[1] = 0.f; }
        else {
            float e2 = expf(v2 - v1);
            sel_w[0] = 1.f / (1.f + e2);
            sel_w[1] = e2 / (1.f + e2);
        }
        sel_e[0] = i1; sel_e[1] = i2;
    }
    __syncthreads();

    for (int kk = 0; kk < 2; kk++){
        int e = sel_e[kk];
        float wgt = sel_w[kk];
        const float* w1p = W1 + (size_t)e * DM * DF;
        for (int j = t; j < DF; j += 256){
            float a = b1[e*DF + j];
            for (int k = 0; k < DM; k++) a += xr[k] * w1p[(size_t)k*DF + j];
            hl[j] = a > 0.f ? a : 0.f;
        }
        __syncthreads();
        const float* w2p = W2 + (size_t)e * DF * DM;
        for (int c = t; c < DM; c += 256){
            float a = b2[e*DM + c];
            for (int k = 0; k < DF; k++) a += hl[k] * w2p[(size_t)k*DM + c];
            yl[c] += wgt * a;
        }
        __syncthreads();
    }
    for (int c = t; c < DM; c += 256) out[(size_t)s*DM + c] = yl[c];
}

extern "C" void kernel_launch(void* const* d_in, const int* in_sizes, int n_in,
                              void* d_out, int out_size, void* d_ws, size_t ws_size,
                              hipStream_t stream) {
    const float* x  = (const float*)d_in[0];
    const float* Wg = (const float*)d_in[1];
    const float* W1 = (const float*)d_in[2];
    const float* b1 = (const float*)d_in[3];
    const float* W2 = (const float*)d_in[4];
    const float* b2 = (const float*)d_in[5];
    float* out = (float*)d_out;

    char* ws = (char*)d_ws;
    int*   counts = (int*)(ws + WS_COUNTS);
    int*   cursor = (int*)(ws + WS_CURSOR);
    int*   offs   = (int*)(ws + WS_OFFS);
    int*   mbe    = (int*)(ws + WS_MBE);
    int*   eid    = (int*)(ws + WS_EID);
    float* gw     = (float*)(ws + WS_GW);
    int*   pos_of = (int*)(ws + WS_POS);
    int*   tok_of = (int*)(ws + WS_TOK);

    const size_t xbB = (size_t)S_TOK*DM*2;           //  6.29 MB
    const size_t wB  = (size_t)NE*DM*DF*2;           // 37.75 MB each
    const size_t hB  = (size_t)PSLOT*DF*2;           // 56.62 MB
    const size_t need = CTRL_BYTES + xbB + 2*wB + hB;  // 138.7 MB

    if (ws_size < need){
        fallback_kernel<<<S_TOK, 256, 0, stream>>>(x, Wg, W1, b1, W2, b2, out);
        return;
    }

    u16* xb  = (u16*)(ws + CTRL_BYTES);
    u16* W1s = (u16*)(ws + CTRL_BYTES + xbB);
    u16* W2s = (u16*)(ws + CTRL_BYTES + xbB + wB);
    u16* h   = (u16*)(ws + CTRL_BYTES + xbB + 2*wB);
    // y (28.3 MB fp32) reuses the W1s region (37.75 MB) — W1s is dead once gemm1 completes,
    // and the next graph replay rewrites W1s via cvtshuf before gemm1 reads it again.
    float* yb = (float*)(ws + CTRL_BYTES + xbB);

    cvtx_kernel<<<S_TOK*DM/8/256, 256, 0, stream>>>(x, xb, counts, cursor);
    cvtshuf_kernel<<<dim3((DM/32)*(DF/128), NE), 256, 0, stream>>>(W1, W1s, DM, DF);
    cvtshuf_kernel<<<dim3((DF/32)*(DM/128), NE), 256, 0, stream>>>(W2, W2s, DF, DM);
    gate_kernel<<<GATE_BLOCKS, 256, 0, stream>>>(x, Wg, eid, gw, counts);
    offsets_kernel<<<1, 1, 0, stream>>>(counts, offs, cursor, mbe);
    scatter_kernel<<<PSLOT/256, 256, 0, stream>>>(eid, cursor, counts, offs, mbe, tok_of, pos_of);

    gemm1u_kernel<<<MBMAX*24, 256, 0, stream>>>(xb, tok_of, mbe, W1s, b1, h);
    gemm2p_kernel<<<6*MBMAX, 256, 0, stream>>>(h, mbe, W2s, b2, yb);
    combine_kernel<<<(S_TOK*(DM/4))/256, 256, 0, stream>>>(yb, pos_of, gw, out);
}

// Round 8
// 344.353 us; speedup vs baseline: 1.1108x; 1.0039x over previous
//
#include <hip/hip_runtime.h>
#include <math.h>

typedef short short8 __attribute__((ext_vector_type(8)));
typedef float f32x4 __attribute__((ext_vector_type(4)));
typedef unsigned short u16;
typedef unsigned int u32;

#define S_TOK 4096
#define DM 768
#define DF 3072
#define NE 8
#define NSLOT (S_TOK*2)      // 8192 real slots
#define PSLOT 9216           // padded capacity (8192 + 8*127 rounded up)
#define MBMAX 72             // PSLOT/128

// ---- control block ----
// counts/cursor are cacheline-padded: expert e lives at [e*16] (64 B stride)
#define WS_COUNTS   0        // 128 ints (8 x 16-int stride)
#define WS_CURSOR   512      // 128 ints
#define WS_OFFS     1024     // 9 ints (padded expert starts)
#define WS_MBE      1088     // MBMAX ints (mb -> expert, -1 = dead)
#define WS_EID      2048     // NSLOT ints
#define WS_GW       (WS_EID + NSLOT*4)
#define WS_POS      (WS_GW  + NSLOT*4)      // NSLOT ints: slot position of (token,k)
#define WS_TOK      (WS_POS + NSLOT*4)      // PSLOT ints
#define CTRL_BYTES  262144

#define AS1 __attribute__((address_space(1)))
#define AS3 __attribute__((address_space(3)))
#define GLDS16(g, s) __builtin_amdgcn_global_load_lds((const AS1 u32*)(g), (AS3 u32*)(s), 16, 0, 0)

__device__ inline u16 f2b(float f){
    u32 u = __builtin_bit_cast(u32, f);
    u32 r = (u + 0x7fffu + ((u >> 16) & 1u)) >> 16;   // RNE
    return (u16)r;
}

// ---------------- W fp32 [e][K][N] -> bf16 fragment order, direct gather (no LDS) ----------------
// out[((nb*8+nt)*kbn+kb)*512 + l*8 + j] = W[kb*32+(l>>4)*8+j][nb*128+nt*16+(l&15)]
// Each thread handles the (nt, nt+1) pair so a wave consumes full 128B lines per row.
// W1 and W2 in one launch: b < 576 -> W1, else W2. Block (0,0) also inits counts/cursor.
__global__ __launch_bounds__(256) void cvtw_kernel(const float* __restrict__ W1, u16* __restrict__ W1s,
                                                   const float* __restrict__ W2, u16* __restrict__ W2s,
                                                   int* __restrict__ counts, int* __restrict__ cursor){
    if (blockIdx.x == 0 && blockIdx.y == 0 && threadIdx.x < 128){
        counts[threadIdx.x] = 0; cursor[threadIdx.x] = 0;
    }
    int e = blockIdx.y;
    int b = blockIdx.x;
    const float* Wp; u16* Wsp; int Kd, Nd;
    if (b < 576){ Wp = W1; Wsp = W1s; Kd = DM; Nd = DF; }
    else        { b -= 576; Wp = W2; Wsp = W2s; Kd = DF; Nd = DM; }
    int kbn = Kd >> 5;
    Wp  += (size_t)e*Kd*Nd;
    Wsp += (size_t)e*Kd*Nd;
    int t = threadIdx.x;
    int u = b*256 + t;          // pair index: Kd*Nd/16 pairs = 576 blocks each
    int l   = u & 63;
    int kb  = (u >> 6) % kbn;
    int qq  = (u >> 6) / kbn;   // nb*4 + ntp
    int ntp = qq & 3;
    int nb  = qq >> 2;
    int k0 = kb*32 + (l >> 4)*8;
    int c  = nb*128 + ntp*32 + (l & 15);
    const float* src = Wp + (size_t)k0*Nd + c;
    short8 o0, o1;
#pragma unroll
    for (int j = 0; j < 8; j++){
        o0[j] = (short)f2b(src[(size_t)j*Nd]);
        o1[j] = (short)f2b(src[(size_t)j*Nd + 16]);
    }
    size_t v0 = ((size_t)(nb*8 + ntp*2)*kbn + kb)*64 + l;
    *(short8*)&Wsp[v0*8] = o0;
    *(short8*)&Wsp[v0*8 + (size_t)kbn*512] = o1;
}

// ---------------- gate (+ x fp32->bf16 fused): grid-stride waves + LDS histogram ----------------
#define GATE_BLOCKS 128
__global__ __launch_bounds__(256) void gate_kernel(const float* __restrict__ x, const float* __restrict__ Wg,
                                                   int* __restrict__ eid, float* __restrict__ gw,
                                                   int* __restrict__ counts, u16* __restrict__ xb){
    __shared__ int lh[NE];
    int t = threadIdx.x;
    if (t < NE) lh[t] = 0;
    __syncthreads();
    int wv = t >> 6, l = t & 63;
    int wgid = blockIdx.x*4 + wv;            // 0 .. GATE_BLOCKS*4-1
    const int NW = GATE_BLOCKS*4;

    for (int s = wgid; s < S_TOK; s += NW){
        float acc[NE];
#pragma unroll
        for (int e = 0; e < NE; e++) acc[e] = 0.f;
        const float* xr = x + (size_t)s * DM;
        u16* xbr = xb + (size_t)s * DM;
#pragma unroll
        for (int i = 0; i < DM/64; i++){
            int d = l + 64*i;
            float xv = xr[d];
            xbr[d] = f2b(xv);
            float4 w0 = *(const float4*)(Wg + d*NE);
            float4 w1 = *(const float4*)(Wg + d*NE + 4);
            acc[0] += xv*w0.x; acc[1] += xv*w0.y; acc[2] += xv*w0.z; acc[3] += xv*w0.w;
            acc[4] += xv*w1.x; acc[5] += xv*w1.y; acc[6] += xv*w1.z; acc[7] += xv*w1.w;
        }
#pragma unroll
        for (int e = 0; e < NE; e++){
#pragma unroll
            for (int off = 32; off; off >>= 1) acc[e] += __shfl_down(acc[e], off);
        }
        if (l == 0){
            int i1 = 0; float v1 = acc[0];
            for (int e = 1; e < NE; e++) if (acc[e] > v1){ v1 = acc[e]; i1 = e; }
            int i2 = -1; float v2 = -1e30f;
            for (int e = 0; e < NE; e++) if (e != i1 && acc[e] > v2){ v2 = acc[e]; i2 = e; }
            float w0, w1;
            if (i2 < 0){ i2 = (i1 + 1) & 7; w0 = 1.f; w1 = 0.f; }
            else {
                float e2 = expf(v2 - v1);
                w0 = 1.f / (1.f + e2);
                w1 = e2 / (1.f + e2);
            }
            eid[2*s]   = i1; gw[2*s]   = w0;
            eid[2*s+1] = i2; gw[2*s+1] = w1;
            atomicAdd(&lh[i1], 1);
            atomicAdd(&lh[i2], 1);
        }
    }
    __syncthreads();
    if (t < NE && lh[t] > 0) atomicAdd(&counts[t*16], lh[t]);
}

// ---------------- offsets with capacity padding + mb->expert map ----------------
__global__ void offsets_kernel(const int* __restrict__ counts, int* __restrict__ offs,
                               int* __restrict__ cursor, int* __restrict__ mbe){
    if (threadIdx.x == 0 && blockIdx.x == 0){
        int P = 0;
        for (int e = 0; e < NE; e++){
            offs[e] = P; cursor[e*16] = P;
            int padded = ((counts[e*16] + 127) >> 7) << 7;
            for (int mb = P >> 7; mb < (P + padded) >> 7; mb++) mbe[mb] = e;
            P += padded;
        }
        offs[NE] = P;
        for (int mb = P >> 7; mb < MBMAX; mb++) mbe[mb] = -1;
    }
}

// ---------------- scatter + padfill merged (grid = PSLOT/256) ----------------
__global__ __launch_bounds__(256) void scatter_kernel(const int* __restrict__ eid, int* __restrict__ cursor,
                                                      const int* __restrict__ counts, const int* __restrict__ offs,
                                                      const int* __restrict__ mbe,
                                                      int* __restrict__ tok_of, int* __restrict__ pos_of){
    __shared__ int lh[NE];
    __shared__ int base[NE];
    int t = threadIdx.x;
    if (t < NE) lh[t] = 0;
    __syncthreads();
    int i = blockIdx.x*256 + t;
    int e = 0, r = 0;
    if (i < NSLOT){
        e = eid[i];
        if (e < 0) e = 0; if (e > 7) e = 7;
        r = atomicAdd(&lh[e], 1);          // rank within block for this expert
    }
    __syncthreads();
    if (t < NE) base[t] = (lh[t] > 0) ? atomicAdd(&cursor[t*16], lh[t]) : 0;
    __syncthreads();
    if (i < NSLOT){
        int p = base[e] + r;
        if (p < 0) p = 0; if (p >= PSLOT) p = PSLOT - 1;
        tok_of[p] = i >> 1;
        pos_of[i] = p;
    }
    // padfill part: p = i in [0, PSLOT)
    int p = i;
    int pe = mbe[p >> 7];
    if (pe < 0){ tok_of[p] = 0; }
    else if (p >= offs[pe] + counts[pe*16]){ tok_of[p] = 0; }
}

// ---------------- GEMM1: h = relu(x[tok] @ W1[e] + b1[e]) ----------------
// Counted-vmcnt 2-buffer pipeline (LDS 50KB -> 3 blocks/CU kept): A regs loaded 2 steps
// ahead so each wait is vmcnt(4) retiring exactly the older quad; tail waits vmcnt(0) once.
__global__ __launch_bounds__(256) void gemm1p_kernel(const u16* __restrict__ xb, const int* __restrict__ tok_of,
                                                     const int* __restrict__ mbe, const u16* __restrict__ W1s,
                                                     const float* __restrict__ b1, u16* __restrict__ h){
    const int KB = DM/32;     // 24 kblks
    const int NT = DM/64;     // 12 double-steps
    int bid = blockIdx.x;
    int by = bid % 24, mb = bid / 24;   // XCD = bid%8 = by%8 -> B strips L2-local per XCD
    int e = mbe[mb];
    if (e < 0) return;
    int m0 = mb*128, n0 = by*128;

    int t = threadIdx.x;
    int w = t >> 6, l = t & 63;
    int wm = w & 1, wn = w >> 1;

    __shared__ u16 As[128*72];        // 18 KB, single buffer
    __shared__ u16 Bs[2*2*8*512];     // 32 KB: [buf][ks][ntile][lane*8]

    int row0 = t >> 2, kc = t & 3;
    const u16* a0 = xb + (size_t)tok_of[m0 + row0]*DM + kc*8;
    const u16* a1 = xb + (size_t)tok_of[m0 + row0 + 64]*DM + kc*8;
    u16* as0 = &As[row0*72 + kc*8];
    u16* as1 = &As[(row0 + 64)*72 + kc*8];

    const u16* bbase = W1s + (size_t)e*DM*DF + (size_t)(((n0 >> 4) + 2*w)*KB)*512 + l*8;

#define STB1(kb2, buf) do{ \
    GLDS16(bbase + (size_t)(2*(kb2))*512,                   &Bs[(buf)*8192 + (2*w)*512]); \
    GLDS16(bbase + (size_t)(2*(kb2)+1)*512,                 &Bs[(buf)*8192 + 4096 + (2*w)*512]); \
    GLDS16(bbase + (size_t)KB*512 + (size_t)(2*(kb2))*512,  &Bs[(buf)*8192 + (2*w+1)*512]); \
    GLDS16(bbase + (size_t)KB*512 + (size_t)(2*(kb2)+1)*512,&Bs[(buf)*8192 + 4096 + (2*w+1)*512]); \
}while(0)

    f32x4 acc[4][4];
#pragma unroll
    for (int i = 0; i < 4; i++)
#pragma unroll
        for (int j = 0; j < 4; j++) acc[i][j] = (f32x4){0.f,0.f,0.f,0.f};

    // prologue: A(0)->regs [4], G(0)->buf0 [4], As<-A(0) (compiler retires A(0)), A(1)->regs [4]
    short8 av0a = *(const short8*)a0;
    short8 av0b = *(const short8*)(a0 + 32);
    short8 av1a = *(const short8*)a1;
    short8 av1b = *(const short8*)(a1 + 32);
    STB1(0, 0);
    *(short8*)as0 = av0a; *(short8*)(as0 + 32) = av0b;
    *(short8*)as1 = av1a; *(short8*)(as1 + 32) = av1b;
    av0a = *(const short8*)(a0 + 64);
    av0b = *(const short8*)(a0 + 96);
    av1a = *(const short8*)(a1 + 64);
    av1b = *(const short8*)(a1 + 96);
    // outstanding: G0(4, oldest), A1(4, newest) -> vmcnt(4): G0 landed
    __builtin_amdgcn_sched_barrier(0);
    asm volatile("s_waitcnt vmcnt(4) lgkmcnt(0)" ::: "memory");
    __builtin_amdgcn_sched_barrier(0);
    __builtin_amdgcn_s_barrier();

    int cb = 0;
    for (int kt = 0; kt < NT; kt++){
        if (kt + 1 < NT) STB1(kt + 1, cb ^ 1);
#pragma unroll
        for (int ks = 0; ks < 2; ks++){
            short8 af[4], bf[4];
#pragma unroll
            for (int mt = 0; mt < 4; mt++)
                af[mt] = *(const short8*)&As[(wm*64 + mt*16 + (l & 15))*72 + ks*32 + (l >> 4)*8];
#pragma unroll
            for (int nt = 0; nt < 4; nt++)
                bf[nt] = *(const short8*)&Bs[cb*8192 + ks*4096 + (wn*4 + nt)*512 + l*8];
#pragma unroll
            for (int mt = 0; mt < 4; mt++)
#pragma unroll
                for (int nt = 0; nt < 4; nt++)
                    acc[mt][nt] = __builtin_amdgcn_mfma_f32_16x16x32_bf16(af[mt], bf[nt], acc[mt][nt], 0, 0, 0);
        }
        // outstanding: A(kt+1)[4 oldest], G(kt+1)[4 newest] -> vmcnt(4): A(kt+1) retired (for As write).
        __builtin_amdgcn_sched_barrier(0);
        asm volatile("s_waitcnt vmcnt(4) lgkmcnt(0)" ::: "memory");
        __builtin_amdgcn_sched_barrier(0);
        __builtin_amdgcn_s_barrier();
        if (kt + 1 < NT){
            *(short8*)as0 = av0a; *(short8*)(as0 + 32) = av0b;
            *(short8*)as1 = av1a; *(short8*)(as1 + 32) = av1b;
            if (kt + 2 < NT){
                av0a = *(const short8*)(a0 + (kt+2)*64);
                av0b = *(const short8*)(a0 + (kt+2)*64 + 32);
                av1a = *(const short8*)(a1 + (kt+2)*64);
                av1b = *(const short8*)(a1 + (kt+2)*64 + 32);
                // outstanding: G(kt+1)[4 oldest], A(kt+2)[4 newest] -> vmcnt(4): G(kt+1) landed
                __builtin_amdgcn_sched_barrier(0);
                asm volatile("s_waitcnt vmcnt(4) lgkmcnt(0)" ::: "memory");
                __builtin_amdgcn_sched_barrier(0);
            } else {
                // tail: only G(kt+1) in flight -> must drain fully
                __builtin_amdgcn_sched_barrier(0);
                asm volatile("s_waitcnt vmcnt(0) lgkmcnt(0)" ::: "memory");
                __builtin_amdgcn_sched_barrier(0);
            }
            __builtin_amdgcn_s_barrier();
        }
        cb ^= 1;
    }
#undef STB1

#pragma unroll
    for (int nt = 0; nt < 4; nt++){
        int col = n0 + wn*64 + nt*16 + (l & 15);
        float bv = b1[e*DF + col];
#pragma unroll
        for (int mt = 0; mt < 4; mt++){
#pragma unroll
            for (int r = 0; r < 4; r++){
                int grow = m0 + wm*64 + mt*16 + (l >> 4)*4 + r;
                float v = acc[mt][nt][r] + bv;
                v = v > 0.f ? v : 0.f;
                h[(size_t)grow*DF + col] = f2b(v);
            }
        }
    }
}

// ---------------- GEMM2: y[slot] = h[slot] @ W2[e] + b2[e] ----------------
// 128x128 tile, counted-vmcnt 3-buffer pipeline (unchanged from r7, verified).
__global__ __launch_bounds__(256) void gemm2p_kernel(const u16* __restrict__ h, const int* __restrict__ mbe,
                                                     const u16* __restrict__ W2s, const float* __restrict__ b2,
                                                     float* __restrict__ y){
    const int KB = DF/32;     // 96 kblks
    const int NT = DF/64;     // 48 double-steps
    int bid = blockIdx.x;
    int mb = bid % MBMAX;     // XCD = bid%8 = mb%8 -> A rows (h) L2-local per XCD
    int by = bid / MBMAX;     // 0..5
    int e = mbe[mb];
    if (e < 0) return;
    int m0 = mb*128, n0 = by*128;

    int t = threadIdx.x;
    int w = t >> 6, l = t & 63;
    int wm = w & 1, wn = w >> 1;

    __shared__ u16 As[128*72];        // 18 KB
    __shared__ u16 Bs[3*2*8*512];     // 48 KB: [buf][ks][ntile][lane*8]

    int row0 = t >> 2, kc = t & 3;
    const u16* a0 = h + (size_t)(m0 + row0)*DF + kc*8;
    const u16* a1 = h + (size_t)(m0 + row0 + 64)*DF + kc*8;
    u16* as0 = &As[row0*72 + kc*8];
    u16* as1 = &As[(row0 + 64)*72 + kc*8];

    const u16* bbase = W2s + (size_t)e*DF*DM + (size_t)(((n0 >> 4) + 2*w)*KB)*512 + l*8;

#define STB2(kb2, buf) do{ \
    GLDS16(bbase + (size_t)(2*(kb2))*512,                   &Bs[(buf)*8192 + (2*w)*512]); \
    GLDS16(bbase + (size_t)(2*(kb2)+1)*512,                 &Bs[(buf)*8192 + 4096 + (2*w)*512]); \
    GLDS16(bbase + (size_t)KB*512 + (size_t)(2*(kb2))*512,  &Bs[(buf)*8192 + (2*w+1)*512]); \
    GLDS16(bbase + (size_t)KB*512 + (size_t)(2*(kb2)+1)*512,&Bs[(buf)*8192 + 4096 + (2*w+1)*512]); \
}while(0)

    f32x4 acc[4][4];
#pragma unroll
    for (int i = 0; i < 4; i++)
#pragma unroll
        for (int j = 0; j < 4; j++) acc[i][j] = (f32x4){0.f,0.f,0.f,0.f};

    // prologue: A(0)->regs, G(0)->buf0, G(1)->buf1, As<-A(0), A(1)->regs
    short8 av0a = *(const short8*)a0;
    short8 av0b = *(const short8*)(a0 + 32);
    short8 av1a = *(const short8*)a1;
    short8 av1b = *(const short8*)(a1 + 32);
    STB2(0, 0);
    STB2(1, 1);
    *(short8*)as0 = av0a; *(short8*)(as0 + 32) = av0b;   // compiler waits A(0) regs only
    *(short8*)as1 = av1a; *(short8*)(as1 + 32) = av1b;
    av0a = *(const short8*)(a0 + 64);
    av0b = *(const short8*)(a0 + 96);
    av1a = *(const short8*)(a1 + 64);
    av1b = *(const short8*)(a1 + 96);
    // outstanding: G0(4,oldest), G1(4), A1(4,newest) -> vmcnt(8): G0 landed
    __builtin_amdgcn_sched_barrier(0);
    asm volatile("s_waitcnt vmcnt(8) lgkmcnt(0)" ::: "memory");
    __builtin_amdgcn_sched_barrier(0);
    __builtin_amdgcn_s_barrier();

    int cb = 0, sb = 2;   // compute buf, stage buf (t+2)
    for (int kt = 0; kt < NT; kt++){
        if (kt + 2 < NT) STB2(kt + 2, sb);
#pragma unroll
        for (int ks = 0; ks < 2; ks++){
            short8 af[4], bf[4];
#pragma unroll
            for (int mt = 0; mt < 4; mt++)
                af[mt] = *(const short8*)&As[(wm*64 + mt*16 + (l & 15))*72 + ks*32 + (l >> 4)*8];
#pragma unroll
            for (int nt = 0; nt < 4; nt++)
                bf[nt] = *(const short8*)&Bs[cb*8192 + ks*4096 + (wn*4 + nt)*512 + l*8];
#pragma unroll
            for (int mt = 0; mt < 4; mt++)
#pragma unroll
                for (int nt = 0; nt < 4; nt++)
                    acc[mt][nt] = __builtin_amdgcn_mfma_f32_16x16x32_bf16(af[mt], bf[nt], acc[mt][nt], 0, 0, 0);
        }
        // in-flight: G(t+1) oldest, A(t+1), G(t+2) newest -> vmcnt(4): G(t+1)+A(t+1) done.
        __builtin_amdgcn_sched_barrier(0);
        asm volatile("s_waitcnt vmcnt(4) lgkmcnt(0)" ::: "memory");
        __builtin_amdgcn_sched_barrier(0);
        __builtin_amdgcn_s_barrier();
        if (kt + 1 < NT){
            *(short8*)as0 = av0a; *(short8*)(as0 + 32) = av0b;
            *(short8*)as1 = av1a; *(short8*)(as1 + 32) = av1b;
            if (kt + 2 < NT){
                av0a = *(const short8*)(a0 + (kt+2)*64);
                av0b = *(const short8*)(a0 + (kt+2)*64 + 32);
                av1a = *(const short8*)(a1 + (kt+2)*64);
                av1b = *(const short8*)(a1 + (kt+2)*64 + 32);
            }
            __builtin_amdgcn_sched_barrier(0);
            asm volatile("s_waitcnt lgkmcnt(0)" ::: "memory");
            __builtin_amdgcn_sched_barrier(0);
            __builtin_amdgcn_s_barrier();
        }
        cb = (cb == 2) ? 0 : cb + 1;
        sb = (sb == 2) ? 0 : sb + 1;
    }
#undef STB2

#pragma unroll
    for (int nt = 0; nt < 4; nt++){
        int col = n0 + wn*64 + nt*16 + (l & 15);
        float bv = b2[e*DM + col];
#pragma unroll
        for (int mt = 0; mt < 4; mt++){
#pragma unroll
            for (int r = 0; r < 4; r++){
                int grow = m0 + wm*64 + mt*16 + (l >> 4)*4 + r;
                y[(size_t)grow*DM + col] = acc[mt][nt][r] + bv;
            }
        }
    }
}

// ---------------- combine: out[s] = w0*y[pos(s,0)] + w1*y[pos(s,1)] ----------------
__global__ __launch_bounds__(256) void combine_kernel(const float* __restrict__ y, const int* __restrict__ pos_of,
                                                      const float* __restrict__ gw, float* __restrict__ out){
    int i = blockIdx.x*256 + threadIdx.x;   // float4 index
    int s = i / (DM/4);
    int c4 = (i - s*(DM/4))*4;
    int p0 = pos_of[2*s], p1 = pos_of[2*s+1];
    float w0 = gw[2*s], w1 = gw[2*s+1];
    float4 a = *(const float4*)&y[(size_t)p0*DM + c4];
    float4 b = *(const float4*)&y[(size_t)p1*DM + c4];
    float4 o;
    o.x = w0*a.x + w1*b.x;
    o.y = w0*a.y + w1*b.y;
    o.z = w0*a.z + w1*b.z;
    o.w = w0*a.w + w1*b.w;
    *(float4*)&out[(size_t)s*DM + c4] = o;
}

// ---------------- zero-workspace fallback ----------------
__global__ __launch_bounds__(256) void fallback_kernel(const float* __restrict__ x, const float* __restrict__ Wg,
                                                       const float* __restrict__ W1, const float* __restrict__ b1,
                                                       const float* __restrict__ W2, const float* __restrict__ b2,
                                                       float* __restrict__ out){
    int s = blockIdx.x;
    int t = threadIdx.x;
    __shared__ float xr[DM];
    __shared__ float hl[DF];
    __shared__ float yl[DM];
    __shared__ float lacc[4*NE];
    __shared__ int   sel_e[2];
    __shared__ float sel_w[2];

    for (int i = t; i < DM; i += 256){ xr[i] = x[(size_t)s*DM + i]; yl[i] = 0.f; }
    __syncthreads();

    float acc[NE];
#pragma unroll
    for (int e = 0; e < NE; e++) acc[e] = 0.f;
    for (int d = t*3; d < t*3 + 3; d++){
        float xv = xr[d];
#pragma unroll
        for (int e = 0; e < NE; e++) acc[e] += xv * Wg[d*NE + e];
    }
#pragma unroll
    for (int e = 0; e < NE; e++){
#pragma unroll
        for (int off = 32; off; off >>= 1) acc[e] += __shfl_down(acc[e], off);
    }
    if ((t & 63) == 0){
        int wv = t >> 6;
#pragma unroll
        for (int e = 0; e < NE; e++) lacc[wv*NE + e] = acc[e];
    }
    __syncthreads();
    if (t == 0){
        float lg[NE];
#pragma unroll
        for (int e = 0; e < NE; e++) lg[e] = lacc[e] + lacc[NE + e] + lacc[2*NE + e] + lacc[3*NE + e];
        int i1 = 0; float v1 = lg[0];
        for (int e = 1; e < NE; e++) if (lg[e] > v1){ v1 = lg[e]; i1 = e; }
        int i2 = -1; float v2 = -1e30f;
        for (int e = 0; e < NE; e++) if (e != i1 && lg[e] > v2){ v2 = lg[e]; i2 = e; }
        if (i2 < 0){ i2 = (i1 + 1) & 7; sel_w[0] = 1.f; sel_w[1] = 0.f; }
        else {
            float e2 = expf(v2 - v1);
            sel_w[0] = 1.f / (1.f + e2);
            sel_w[1] = e2 / (1.f + e2);
        }
        sel_e[0] = i1; sel_e[1] = i2;
    }
    __syncthreads();

    for (int kk = 0; kk < 2; kk++){
        int e = sel_e[kk];
        float wgt = sel_w[kk];
        const float* w1p = W1 + (size_t)e * DM * DF;
        for (int j = t; j < DF; j += 256){
            float a = b1[e*DF + j];
            for (int k = 0; k < DM; k++) a += xr[k] * w1p[(size_t)k*DF + j];
            hl[j] = a > 0.f ? a : 0.f;
        }
        __syncthreads();
        const float* w2p = W2 + (size_t)e * DF * DM;
        for (int c = t; c < DM; c += 256){
            float a = b2[e*DM + c];
            for (int k = 0; k < DF; k++) a += hl[k] * w2p[(size_t)k*DM + c];
            yl[c] += wgt * a;
        }
        __syncthreads();
    }
    for (int c = t; c < DM; c += 256) out[(size_t)s*DM + c] = yl[c];
}

extern "C" void kernel_launch(void* const* d_in, const int* in_sizes, int n_in,
                              void* d_out, int out_size, void* d_ws, size_t ws_size,
                              hipStream_t stream) {
    const float* x  = (const float*)d_in[0];
    const float* Wg = (const float*)d_in[1];
    const float* W1 = (const float*)d_in[2];
    const float* b1 = (const float*)d_in[3];
    const float* W2 = (const float*)d_in[4];
    const float* b2 = (const float*)d_in[5];
    float* out = (float*)d_out;

    char* ws = (char*)d_ws;
    int*   counts = (int*)(ws + WS_COUNTS);
    int*   cursor = (int*)(ws + WS_CURSOR);
    int*   offs   = (int*)(ws + WS_OFFS);
    int*   mbe    = (int*)(ws + WS_MBE);
    int*   eid    = (int*)(ws + WS_EID);
    float* gw     = (float*)(ws + WS_GW);
    int*   pos_of = (int*)(ws + WS_POS);
    int*   tok_of = (int*)(ws + WS_TOK);

    const size_t xbB = (size_t)S_TOK*DM*2;           //  6.29 MB
    const size_t wB  = (size_t)NE*DM*DF*2;           // 37.75 MB each
    const size_t hB  = (size_t)PSLOT*DF*2;           // 56.62 MB
    const size_t need = CTRL_BYTES + xbB + 2*wB + hB;  // 138.7 MB

    if (ws_size < need){
        fallback_kernel<<<S_TOK, 256, 0, stream>>>(x, Wg, W1, b1, W2, b2, out);
        return;
    }

    u16* xb  = (u16*)(ws + CTRL_BYTES);
    u16* W1s = (u16*)(ws + CTRL_BYTES + xbB);
    u16* W2s = (u16*)(ws + CTRL_BYTES + xbB + wB);
    u16* h   = (u16*)(ws + CTRL_BYTES + xbB + 2*wB);
    // y (28.3 MB fp32) reuses the W1s region (37.75 MB) — W1s is dead once gemm1 completes,
    // and the next graph replay rewrites W1s via cvtw before gemm1 reads it again.
    float* yb = (float*)(ws + CTRL_BYTES + xbB);

    cvtw_kernel<<<dim3(1152, NE), 256, 0, stream>>>(W1, W1s, W2, W2s, counts, cursor);
    gate_kernel<<<GATE_BLOCKS, 256, 0, stream>>>(x, Wg, eid, gw, counts, xb);
    offsets_kernel<<<1, 1, 0, stream>>>(counts, offs, cursor, mbe);
    scatter_kernel<<<PSLOT/256, 256, 0, stream>>>(eid, cursor, counts, offs, mbe, tok_of, pos_of);

    gemm1p_kernel<<<MBMAX*24, 256, 0, stream>>>(xb, tok_of, mbe, W1s, b1, h);
    gemm2p_kernel<<<6*MBMAX, 256, 0, stream>>>(h, mbe, W2s, b2, yb);
    combine_kernel<<<(S_TOK*(DM/4))/256, 256, 0, stream>>>(yb, pos_of, gw, out);
}